// Round 2
// baseline (428.810 us; speedup 1.0000x reference)
//
#include <hip/hip_runtime.h>
#include <stdint.h>

// ---------------------------------------------------------------------------
// FineReviewDecoderAttention: q/k/v proj (f32-A direct-staged bf16 MFMA GEMM,
// counted-vmcnt 2-buffer pipeline + T2 bank-swizzle) -> fused attention ->
// out proj.  B=32 Q=128 D=1024 H=16 d=64 R=20 T=64.
// Delta vs round 14 (passed, 422.0us): the three cvt_bf16 streaming passes
// (~88us: 160MB rd + 80MB wr each for K/V) are eliminated.  Q/K/V GEMMs now
// stage A as f32 via global_load_lds (4 loads/thread/K-step, own XOR swizzle
// (row&7)<<4 on 128B rows pre-applied to the GLOBAL column, linear LDS dest)
// and convert f32->bf16 at fragment-load time with pack2 (RNE) -- the SAME
// rounding cvt_bf16 used, so MFMA inputs are bit-identical to round 14.
// Sync structure unchanged: stage = 6 loads -> vmcnt(6)/vmcnt(0) (same
// 2-tile-deep ledger proof as the proven vmcnt(4) bf16 path).  Out-proj
// keeps the bf16-A path (ADT=1).  attn2 unchanged (active-review skip).
// ---------------------------------------------------------------------------

typedef __attribute__((ext_vector_type(8))) short bf16x8;
typedef __attribute__((ext_vector_type(4))) float f32x4;
typedef __attribute__((ext_vector_type(4))) unsigned int u32x4;
typedef __attribute__((address_space(1))) const unsigned int as1_t;
typedef __attribute__((address_space(3))) unsigned int as3_t;

#define DEVI static __device__ __forceinline__

DEVI unsigned short f2bf(float f) {  // RNE f32->bf16 (finite inputs)
  unsigned int u = __float_as_uint(f);
  u += 0x7fffu + ((u >> 16) & 1u);
  return (unsigned short)(u >> 16);
}
DEVI unsigned int pack2(float a, float b) {
  return (unsigned int)f2bf(a) | ((unsigned int)f2bf(b) << 16);
}
// Round-half-up bf16 pair pack (proven rounds 7-14): a -> lo16, b -> hi16.
DEVI unsigned int pk2_rhu(float a, float b) {
  unsigned int ua = __float_as_uint(a) + 0x8000u;
  unsigned int ub = __float_as_uint(b) + 0x8000u;
  return (ua >> 16) | (ub & 0xffff0000u);
}

DEVI bf16x8 u2bf(u32x4 v) {
  union { u32x4 u; bf16x8 b; } c;
  c.u = v;
  return c.b;
}

DEVI void gload_lds16(const void* g, void* l) {
  __builtin_amdgcn_global_load_lds((as1_t*)g, (as3_t*)l, 16, 0, 0);
}

DEVI float fast_tanh(float x) {  // round-5-proven form
  float ax = fabsf(x);
  float e = __expf(2.0f * ax);
  float r = __builtin_fmaf(-2.0f, __builtin_amdgcn_rcpf(e + 1.0f), 1.0f);
  return copysignf(r, x);
}

// ------------------------- weight f32 -> bf16 ------------------------------
__global__ void cvt_w4(const float* __restrict__ w0, const float* __restrict__ w1,
                       const float* __restrict__ w2, const float* __restrict__ w3,
                       unsigned short* __restrict__ o0, unsigned short* __restrict__ o1,
                       unsigned short* __restrict__ o2, unsigned short* __restrict__ o3) {
  int i = blockIdx.x * 256 + threadIdx.x;
  if (i >= 262144) return;
  f32x4 v;
  uint2 a;
  v = ((const f32x4*)w0)[i]; a.x = pack2(v[0], v[1]); a.y = pack2(v[2], v[3]);
  *(uint2*)(o0 + 4 * (size_t)i) = a;
  v = ((const f32x4*)w1)[i]; a.x = pack2(v[0], v[1]); a.y = pack2(v[2], v[3]);
  *(uint2*)(o1 + 4 * (size_t)i) = a;
  v = ((const f32x4*)w2)[i]; a.x = pack2(v[0], v[1]); a.y = pack2(v[2], v[3]);
  *(uint2*)(o2 + 4 * (size_t)i) = a;
  v = ((const f32x4*)w3)[i]; a.x = pack2(v[0], v[1]); a.y = pack2(v[2], v[3]);
  *(uint2*)(o3 + 4 * (size_t)i) = a;
}

// ---------------- C[m,n] = sum_k A[m,k]*W[n,k] + bias[n] -------------------
// OUT_MODE: 0 = f32 row-major, 1 = bf16 row-major, 2 = bf16 per-head V^T.
// ADT: 0 = A is f32 (direct gload_lds staging, RNE convert at frag load);
//      1 = A is bf16 (round-12-proven path).  SC=1: epilogue x0.125.
// Both paths: counted-vmcnt 2-buffer pipeline, bank-swizzled LDS tiles.
template <int OUT_MODE, int ADT, int SC>
__global__ __launch_bounds__(256, 4) void gemm_bt(
    const void* __restrict__ Ain, const unsigned short* __restrict__ W,
    const float* __restrict__ bias, void* __restrict__ Cout, int N, int K, int nnt) {
  // ADT=1: A bf16 2x8KB + B 2x8KB = 32KB.  ADT=0: A f32 2x16KB + B 2x8KB = 48KB.
  __shared__ __align__(16) char smem[ADT ? 32768 : 49152];
  char* Asb = smem;
  char* Bsb = smem + (ADT ? 16384 : 32768);
  const int ABSTR = ADT ? 8192 : 16384;  // per-buffer A bytes
  const int tid = (int)threadIdx.x;
  const int lane = tid & 63, wave = tid >> 6;
  const int lm = lane & 15, l4 = lane >> 4;
  const int nb = (int)gridDim.x;
  const int bx = (int)blockIdx.x;
  const int lg = (bx & 7) * (nb >> 3) + (bx >> 3);
  const int mt = lg / nnt, nt = lg % nnt;
  const int wr = wave >> 1, wc = wave & 1;

  f32x4 zero4 = {0.f, 0.f, 0.f, 0.f};
  f32x4 acc[4][4];
#pragma unroll
  for (int i = 0; i < 4; ++i)
#pragma unroll
    for (int j = 0; j < 4; ++j) acc[i][j] = zero4;

  // ---- B staging mapping (both paths): row = tid>>2, 16B chunk = tid&3.
  // T2 swizzle: chunk (row,blk) lives at slot (row, blk ^ ((row>>1)&3)).
  // Linear LDS dest (tid*16) => pre-swizzle the GLOBAL column: scb.
  const int srow = tid >> 2, sblk = tid & 3;
  const int scb = sblk ^ ((srow >> 1) & 3);
  const unsigned short* wpg = W + (size_t)(nt * 128 + srow) * K + scb * 8;
  // fragment-read XOR key for B (and bf16-A): kx = (lm>>1)&3.
  const int kx = (lm >> 1) & 3;

  if (ADT == 0) {
    // ---- A f32 staging mapping: 4 chunks/thread per K-step.
    // chunk u: row = (tid>>3) + 32u, col-chunk cc = tid&7 (16B = 4 floats).
    // Swizzle: LDS chunk (row,cc) holds global chunk cc ^ (row&7); row&7 is
    // (tid>>3)&7 for all u, so the pre-swizzled global column is per-thread.
    const float* apf = (const float*)Ain +
                       (size_t)(mt * 128 + (tid >> 3)) * K +
                       ((tid & 7) ^ ((tid >> 3) & 7)) * 4;
    const int NT = K >> 5;
#pragma unroll
    for (int t0 = 0; t0 < 2; ++t0) {
      const int kt = t0 * 32;
#pragma unroll
      for (int u = 0; u < 4; ++u)
        gload_lds16(apf + (size_t)u * 32 * K + kt, Asb + t0 * 16384 + (tid + u * 256) * 16);
      gload_lds16(wpg + kt, Bsb + t0 * 8192 + tid * 16);
      gload_lds16(wpg + (size_t)64 * K + kt, Bsb + t0 * 8192 + 4096 + tid * 16);
    }
    int cur = 0;
    const int swz = (lm & 7) << 4;
    for (int t = 0; t < NT; ++t) {
      if (t + 1 < NT)
        asm volatile("s_waitcnt vmcnt(6)" ::: "memory");
      else
        asm volatile("s_waitcnt vmcnt(0)" ::: "memory");
      asm volatile("s_barrier" ::: "memory");
      bf16x8 af[4], bfr[4];
#pragma unroll
      for (int i = 0; i < 4; ++i) {
        // A row = wr*64 + i*16 + lm; row&7 == lm&7; 128B f32 rows.
        const char* ab = Asb + cur * 16384 + (wr * 64 + i * 16 + lm) * 128;
        f32x4 lo = *(const f32x4*)(ab + ((l4 * 32) ^ swz));
        f32x4 hi = *(const f32x4*)(ab + ((l4 * 32 + 16) ^ swz));
        u32x4 pv = {pack2(lo[0], lo[1]), pack2(lo[2], lo[3]),
                    pack2(hi[0], hi[1]), pack2(hi[2], hi[3])};
        af[i] = u2bf(pv);
      }
#pragma unroll
      for (int j = 0; j < 4; ++j)
        bfr[j] = *(const bf16x8*)(Bsb + cur * 8192 + (wc * 64 + j * 16 + lm) * 64 +
                                  ((l4 ^ kx) * 16));
#pragma unroll
      for (int i = 0; i < 4; ++i)
#pragma unroll
        for (int j = 0; j < 4; ++j)
          acc[i][j] = __builtin_amdgcn_mfma_f32_16x16x32_bf16(af[i], bfr[j], acc[i][j], 0, 0, 0);
      asm volatile("s_barrier" ::: "memory");
      if (t + 2 < NT) {
        const int kt = (t + 2) * 32;
#pragma unroll
        for (int u = 0; u < 4; ++u)
          gload_lds16(apf + (size_t)u * 32 * K + kt, Asb + cur * 16384 + (tid + u * 256) * 16);
        gload_lds16(wpg + kt, Bsb + cur * 8192 + tid * 16);
        gload_lds16(wpg + (size_t)64 * K + kt, Bsb + cur * 8192 + 4096 + tid * 16);
      }
      cur ^= 1;
    }
  } else {
    // ---- bf16-A path (round-12-proven): counted-vmcnt, swizzled tiles ----
    const unsigned short* apg =
        (const unsigned short*)Ain + (size_t)(mt * 128 + srow) * K + scb * 8;
    const int NT = K >> 5;
#pragma unroll
    for (int t0 = 0; t0 < 2; ++t0) {
      const int kt = t0 * 32;
      gload_lds16(apg + kt, Asb + t0 * 8192 + tid * 16);
      gload_lds16(apg + (size_t)64 * K + kt, Asb + t0 * 8192 + 4096 + tid * 16);
      gload_lds16(wpg + kt, Bsb + t0 * 8192 + tid * 16);
      gload_lds16(wpg + (size_t)64 * K + kt, Bsb + t0 * 8192 + 4096 + tid * 16);
    }
    int cur = 0;
    for (int t = 0; t < NT; ++t) {
      if (t + 1 < NT)
        asm volatile("s_waitcnt vmcnt(4)" ::: "memory");
      else
        asm volatile("s_waitcnt vmcnt(0)" ::: "memory");
      asm volatile("s_barrier" ::: "memory");
      bf16x8 af[4], bfr[4];
#pragma unroll
      for (int i = 0; i < 4; ++i)
        af[i] = *(const bf16x8*)(Asb + cur * 8192 + (wr * 64 + i * 16 + lm) * 64 +
                                 ((l4 ^ kx) * 16));
#pragma unroll
      for (int j = 0; j < 4; ++j)
        bfr[j] = *(const bf16x8*)(Bsb + cur * 8192 + (wc * 64 + j * 16 + lm) * 64 +
                                  ((l4 ^ kx) * 16));
#pragma unroll
      for (int i = 0; i < 4; ++i)
#pragma unroll
        for (int j = 0; j < 4; ++j)
          acc[i][j] = __builtin_amdgcn_mfma_f32_16x16x32_bf16(af[i], bfr[j], acc[i][j], 0, 0, 0);
      asm volatile("s_barrier" ::: "memory");
      if (t + 2 < NT) {
        const int kt = (t + 2) * 32;
        gload_lds16(apg + kt, Asb + cur * 8192 + tid * 16);
        gload_lds16(apg + (size_t)64 * K + kt, Asb + cur * 8192 + 4096 + tid * 16);
        gload_lds16(wpg + kt, Bsb + cur * 8192 + tid * 16);
        gload_lds16(wpg + (size_t)64 * K + kt, Bsb + cur * 8192 + 4096 + tid * 16);
      }
      cur ^= 1;
    }
  }

  const int r0 = mt * 128 + wr * 64 + l4 * 4;
  const int c0 = nt * 128 + wc * 64 + lm;
  float bb[4];
#pragma unroll
  for (int j = 0; j < 4; ++j) bb[j] = bias[c0 + j * 16];

  if (OUT_MODE < 2) {
#pragma unroll
    for (int i = 0; i < 4; ++i)
#pragma unroll
      for (int j = 0; j < 4; ++j)
#pragma unroll
        for (int p = 0; p < 4; ++p) {
          size_t idx = (size_t)(r0 + i * 16 + p) * N + (size_t)(c0 + j * 16);
          float v = acc[i][j][p] + bb[j];
          if (SC) v *= 0.125f;  // exact exponent shift; bf16(v/8) == bf16(v)/8
          if (OUT_MODE == 1)
            ((unsigned short*)Cout)[idx] = f2bf(v);
          else
            ((float*)Cout)[idx] = v;
        }
  } else {
    // V^T per-head tiles: vt[((b*20+r)*16+h)*4096 + d*64 + t], t = i*16+l4*4+p
    const int grow = mt * 128 + wr * 64;
    const int bidx = grow / 1280;
    const int rv = (grow % 1280) / 64;
    const int hh = (nt * 128 + wc * 64) / 64;
    unsigned short* vt = (unsigned short*)Cout;
    const size_t base = ((size_t)(bidx * 20 + rv) * 16 + hh) * 4096;
#pragma unroll
    for (int j = 0; j < 4; ++j) {
      const int d = lm + j * 16;
#pragma unroll
      for (int i = 0; i < 4; ++i) {
        uint2 wv;
        wv.x = pack2(acc[i][j][0] + bb[j], acc[i][j][1] + bb[j]);
        wv.y = pack2(acc[i][j][2] + bb[j], acc[i][j][3] + bb[j]);
        *(uint2*)(vt + base + (size_t)d * 64 + i * 16 + l4 * 4) = wv;
      }
    }
  }
}

// ----------------------------- fused attention -----------------------------
// One block per (h, b); 8 waves, wave w owns q rows [16w,16w+16).
// Swapped-operand MFMAs so q = lane&15 everywhere; online softmax over r.
// LDS (48KB): kv_s[2][K,V] 32KB; pa_s 16KB; q/sa^T staging overlays.
// Active-review compaction: reviews with mask==1 (when any mask==0 exists in
// row b) have pooled weight exactly 0.0f (expf(-1e30 - max) underflows) ->
// skipped entirely.  Bitmask is uniform per block (depends only on b).
__global__ __launch_bounds__(512, 4) void attn2(
    const unsigned short* __restrict__ qb, const unsigned short* __restrict__ kb,
    const unsigned short* __restrict__ vtg, const int* __restrict__ mask,
    const int* __restrict__ mask2, const float* __restrict__ sa_a,
    const float* __restrict__ sa_b, unsigned short* __restrict__ merged) {
  const int h = (int)blockIdx.x;
  const int b = (int)blockIdx.y;
  const int tid = (int)threadIdx.x;
  const int lane = tid & 63, wave = tid >> 6;
  const int lm = lane & 15, l4 = lane >> 4;
  const int sw = (lm & 7) << 4;

  __shared__ unsigned short kv_s[2][2][64 * 64];  // [buf][0=K [t][d], 1=V^T [d][t]]
  __shared__ unsigned short pa_s[8 * 16 * 64];    // wave-private P/att rows

  char* kvb0 = (char*)kv_s;          // buf stride 16384; V^T at +8192
  char* qreg = (char*)kv_s + 16384;  // q staging region = buf1 (dead after hoist)
  char* satb = (char*)pa_s;          // sa^T staging (dead after hoist)

  // ---- active-review bitmask (uniform across the block) ----
  unsigned am = 0u;
#pragma unroll
  for (int rr = 0; rr < 20; ++rr)
    am |= (mask[b * 20 + rr] == 0) ? (1u << rr) : 0u;
  // az (= some review has mask==0) => only those reviews survive; else all.
  const unsigned act = am ? am : 0xFFFFFu;

  // ---- stage Q into qreg (pre-swizzled source columns) ----
#pragma unroll
  for (int s = 0; s < 2; ++s) {
    int idx = s * 512 + tid, row = idx >> 3, blk = idx & 7;
    int cb = blk ^ (row & 7);
    gload_lds16(qb + (size_t)(b * 128 + row) * 1024 + h * 64 + cb * 8, qreg + idx * 16);
  }
  // ---- stage sa^T into satb: sat[jj][d] = sa_a[d][jj], swizzled ----
#pragma unroll
  for (int s = 0; s < 8; ++s) {
    int idx = s * 512 + tid, jj = idx & 63, d = idx >> 6;
    *(unsigned short*)(satb + jj * 128 + ((d * 2) ^ ((jj & 7) << 4))) =
        f2bf(sa_a[d * 64 + jj]);
  }
  // ---- stage first ACTIVE review K/V into buf0 ----
  const int srow = tid >> 3, sblk = tid & 7;
  const int scb = sblk ^ (srow & 7);
  int r = (int)__builtin_ctz(act);
  unsigned rem = act & (act - 1u);
  gload_lds16(kb + ((size_t)(b * 20 + r) * 64 + srow) * 1024 + h * 64 + scb * 8,
              kvb0 + tid * 16);
  gload_lds16(vtg + ((size_t)(b * 20 + r) * 16 + h) * 4096 + srow * 64 + scb * 8,
              kvb0 + 8192 + tid * 16);

  f32x4 sbv[4];
#pragma unroll
  for (int i = 0; i < 4; ++i) sbv[i] = *(const f32x4*)(sa_b + i * 16 + l4 * 4);

  __syncthreads();  // qreg, satb, buf0 all visible

  // ---- hoist Q B-fragments and sa^T A-fragments to registers ----
  const char* qrp = qreg + (wave * 16 + lm) * 128;
  bf16x8 qf[2];
  qf[0] = *(const bf16x8*)(qrp + ((l4 * 16) ^ sw));
  qf[1] = *(const bf16x8*)(qrp + ((64 + l4 * 16) ^ sw));
  bf16x8 sfr[2][4];
#pragma unroll
  for (int kk = 0; kk < 2; ++kk)
#pragma unroll
    for (int i = 0; i < 4; ++i)
      sfr[kk][i] = *(const bf16x8*)(satb + (i * 16 + lm) * 128 +
                                    ((kk * 64 + l4 * 16) ^ sw));
  asm volatile("s_waitcnt lgkmcnt(0)" ::: "memory");  // hoist reads retired
  __syncthreads();  // all waves done -> qreg/satb reusable as buf1 / P-rows

  char* pw = (char*)pa_s + wave * 2048 + lm * 128;  // wave-private row q=lm

  f32x4 zero4 = {0.f, 0.f, 0.f, 0.f};
  f32x4 Pacc[4];
#pragma unroll
  for (int i = 0; i < 4; ++i) Pacc[i] = zero4;
  float m_run = -3.0e38f, s_run = 0.0f;

  int it = 0;
  for (;;) {
    const int pb = it & 1;
    if (it) __syncthreads();  // buf[pb] staged; all waves done with buf[1-pb]
    const int nr = rem ? (int)__builtin_ctz(rem) : -1;
    if (nr >= 0) {  // stage next active review (flies under this one's compute)
      const int nbuf = pb ^ 1;
      gload_lds16(kb + ((size_t)(b * 20 + nr) * 64 + srow) * 1024 + h * 64 + scb * 8,
                  kvb0 + nbuf * 16384 + tid * 16);
      gload_lds16(vtg + ((size_t)(b * 20 + nr) * 16 + h) * 4096 + srow * 64 + scb * 8,
                  kvb0 + nbuf * 16384 + 8192 + tid * 16);
    }
    const char* kbse = kvb0 + pb * 16384;
    const char* vbse = kvb0 + pb * 16384 + 8192;

    // ---- S^T = mfma(K, Q): rows t, col q (q pre-scaled by 1/8) ----
    f32x4 sc[4];
#pragma unroll
    for (int i = 0; i < 4; ++i) sc[i] = zero4;
    __builtin_amdgcn_s_setprio(1);
#pragma unroll
    for (int kk = 0; kk < 2; ++kk) {
      bf16x8 kf[4];
#pragma unroll
      for (int i = 0; i < 4; ++i)
        kf[i] = *(const bf16x8*)(kbse + (i * 16 + lm) * 128 + ((kk * 64 + l4 * 16) ^ sw));
#pragma unroll
      for (int i = 0; i < 4; ++i)
        sc[i] = __builtin_amdgcn_mfma_f32_16x16x32_bf16(kf[i], qf[kk], sc[i], 0, 0, 0);
    }
    __builtin_amdgcn_s_setprio(0);

    // ---- token mask (scores already scaled) + softmax over t ----
    const int mbase = (b * 20 + r) * 64;
#pragma unroll
    for (int i = 0; i < 4; ++i) {
      int4 m2 = *(const int4*)(mask2 + mbase + i * 16 + l4 * 4);
      sc[i][0] = (m2.x == 0) ? -1e20f : sc[i][0];
      sc[i][1] = (m2.y == 0) ? -1e20f : sc[i][1];
      sc[i][2] = (m2.z == 0) ? -1e20f : sc[i][2];
      sc[i][3] = (m2.w == 0) ? -1e20f : sc[i][3];
    }
    float mx = sc[0][0];
#pragma unroll
    for (int i = 0; i < 4; ++i)
#pragma unroll
      for (int p = 0; p < 4; ++p) mx = fmaxf(mx, sc[i][p]);
    mx = fmaxf(mx, __shfl_xor(mx, 16));
    mx = fmaxf(mx, __shfl_xor(mx, 32));
    float sum = 0.f;
#pragma unroll
    for (int i = 0; i < 4; ++i)
#pragma unroll
      for (int p = 0; p < 4; ++p) {
        float e = __expf(sc[i][p] - mx);
        sc[i][p] = e;
        sum += e;
      }
    sum += __shfl_xor(sum, 16);
    sum += __shfl_xor(sum, 32);
    const float pinv = __builtin_amdgcn_rcpf(sum);

    // ---- P -> wave-private LDS [q][t], packed 8B swizzled writes ----
#pragma unroll
    for (int i = 0; i < 4; ++i) {
      uint2 wv;
      wv.x = pk2_rhu(sc[i][0] * pinv, sc[i][1] * pinv);
      wv.y = pk2_rhu(sc[i][2] * pinv, sc[i][3] * pinv);
      *(uint2*)(pw + ((i * 32 + l4 * 8) ^ sw)) = wv;
    }

    // ---- att^T = mfma(V^T, P): rows d, col q ----
    f32x4 av[4];
#pragma unroll
    for (int i = 0; i < 4; ++i) av[i] = zero4;
    __builtin_amdgcn_s_setprio(1);
#pragma unroll
    for (int kk = 0; kk < 2; ++kk) {
      bf16x8 pf = *(const bf16x8*)(pw + ((kk * 64 + l4 * 16) ^ sw));
      bf16x8 vf[4];
#pragma unroll
      for (int i = 0; i < 4; ++i)
        vf[i] = *(const bf16x8*)(vbse + (i * 16 + lm) * 128 + ((kk * 64 + l4 * 16) ^ sw));
#pragma unroll
      for (int i = 0; i < 4; ++i)
        av[i] = __builtin_amdgcn_mfma_f32_16x16x32_bf16(vf[i], pf, av[i], 0, 0, 0);
    }
    __builtin_amdgcn_s_setprio(0);

    // ---- att -> same wave-private LDS [q][d] (P already consumed) ----
#pragma unroll
    for (int i = 0; i < 4; ++i) {
      uint2 wv;
      wv.x = pk2_rhu(av[i][0], av[i][1]);
      wv.y = pk2_rhu(av[i][2], av[i][3]);
      *(uint2*)(pw + ((i * 32 + l4 * 8) ^ sw)) = wv;
    }

    // ---- e^T = mfma(sa^T, att): rows jj, col q ----
    f32x4 ep[4];
#pragma unroll
    for (int i = 0; i < 4; ++i) ep[i] = zero4;
    __builtin_amdgcn_s_setprio(1);
#pragma unroll
    for (int kk = 0; kk < 2; ++kk) {
      bf16x8 afr = *(const bf16x8*)(pw + ((kk * 64 + l4 * 16) ^ sw));
#pragma unroll
      for (int i = 0; i < 4; ++i)
        ep[i] = __builtin_amdgcn_mfma_f32_16x16x32_bf16(sfr[kk][i], afr, ep[i], 0, 0, 0);
    }
    __builtin_amdgcn_s_setprio(0);
    float a = 0.f;
#pragma unroll
    for (int i = 0; i < 4; ++i)
#pragma unroll
      for (int p = 0; p < 4; ++p) a += fast_tanh(ep[i][p]) * sbv[i][p];
    a += __shfl_xor(a, 16);
    a += __shfl_xor(a, 32);

    // ---- exact online softmax update over active reviews ----
    // All surviving reviews have add_mask == 0, so e_r = a directly.
    const float e_r = a;
    const float mnew = fmaxf(m_run, e_r);
    const float scl = __expf(m_run - mnew);
    const float w = __expf(e_r - mnew);
    s_run = s_run * scl + w;
#pragma unroll
    for (int i = 0; i < 4; ++i)
#pragma unroll
      for (int p = 0; p < 4; ++p) Pacc[i][p] = Pacc[i][p] * scl + w * av[i][p];
    m_run = mnew;

    if (nr < 0) break;
    r = nr;
    rem &= rem - 1u;
    ++it;
  }

  // ---- merged[b*128+q][h*64+d] = bf16(Pacc / s) ----
  const float inv_s = __builtin_amdgcn_rcpf(s_run);
  unsigned short* mrow = merged + (size_t)(b * 128 + wave * 16 + lm) * 1024 + h * 64;
#pragma unroll
  for (int i = 0; i < 4; ++i) {
    uint2 o;
    o.x = pk2_rhu(Pacc[i][0] * inv_s, Pacc[i][1] * inv_s);
    o.y = pk2_rhu(Pacc[i][2] * inv_s, Pacc[i][3] * inv_s);
    *(uint2*)(mrow + i * 16 + l4 * 4) = o;
  }
}

// ---------------------------------------------------------------------------
extern "C" void kernel_launch(void* const* d_in, const int* in_sizes, int n_in,
                              void* d_out, int out_size, void* d_ws, size_t ws_size,
                              hipStream_t stream) {
  (void)in_sizes; (void)n_in; (void)out_size; (void)ws_size;
  const float* query = (const float*)d_in[0];
  const float* key   = (const float*)d_in[1];
  const float* value = (const float*)d_in[2];
  const int*   mask  = (const int*)d_in[3];
  const int*   mask2 = (const int*)d_in[4];
  const float* Wq = (const float*)d_in[5];
  const float* bq = (const float*)d_in[6];
  const float* Wk = (const float*)d_in[7];
  const float* bk = (const float*)d_in[8];
  const float* Wv = (const float*)d_in[9];
  const float* bv = (const float*)d_in[10];
  const float* Wo = (const float*)d_in[11];
  const float* bo = (const float*)d_in[12];
  const float* sa_a = (const float*)d_in[13];
  const float* sa_b = (const float*)d_in[14];

  char* ws = (char*)d_ws;
  size_t off = 0;
  auto carve = [&](size_t bytes) -> char* {
    char* p = ws + off;
    off += (bytes + 255) & ~(size_t)255;
    return p;
  };
  unsigned short* wq_b = (unsigned short*)carve((size_t)1024 * 1024 * 2);
  unsigned short* wk_b = (unsigned short*)carve((size_t)1024 * 1024 * 2);
  unsigned short* wv_b = (unsigned short*)carve((size_t)1024 * 1024 * 2);
  unsigned short* wo_b = (unsigned short*)carve((size_t)1024 * 1024 * 2);
  unsigned short* q_b  = (unsigned short*)carve((size_t)4096 * 1024 * 2);
  unsigned short* k_b  = (unsigned short*)carve((size_t)40960 * 1024 * 2);
  unsigned short* vt_g = (unsigned short*)carve((size_t)40960 * 1024 * 2);
  unsigned short* mrg  = (unsigned short*)carve((size_t)4096 * 1024 * 2);

  cvt_w4<<<1024, 256, 0, stream>>>(Wq, Wk, Wv, Wo, wq_b, wk_b, wv_b, wo_b);

  // f32-A direct GEMMs (no cvt_bf16 passes)
  gemm_bt<1, 0, 1><<<dim3(32 * 8), 256, 0, stream>>>(query, wq_b, bq, q_b, 1024, 1024, 8);
  gemm_bt<1, 0, 0><<<dim3(320 * 8), 256, 0, stream>>>(key, wk_b, bk, k_b, 1024, 1024, 8);
  gemm_bt<2, 0, 0><<<dim3(320 * 8), 256, 0, stream>>>(value, wv_b, bv, vt_g, 1024, 1024, 8);

  attn2<<<dim3(16, 32), 512, 0, stream>>>(q_b, k_b, vt_g, mask, mask2, sa_a, sa_b, mrg);

  // out projection: A (mrg) is bf16 -> proven bf16-A path
  gemm_bt<0, 1, 0><<<dim3(32 * 8), 256, 0, stream>>>(mrg, wo_b, bo, d_out, 1024, 1024, 8);
}

// Round 3
// 412.338 us; speedup vs baseline: 1.0399x; 1.0399x over previous
//
#include <hip/hip_runtime.h>
#include <stdint.h>

// ---------------------------------------------------------------------------
// FineReviewDecoderAttention: q/k/v proj (f32-A direct-staged bf16 MFMA GEMM,
// counted-vmcnt 2-buffer pipeline + proven T2 bank-swizzle) -> fused attn ->
// out proj.  B=32 Q=128 D=1024 H=16 d=64 R=20 T=64.
// Delta vs round 15 (passed, 428.8us; K/V GEMMs 184us each, 1.05e7 bank
// conflicts, VALU-issue 3x round-14): two data-path-local fixes, sync
// structure untouched:
//  (1) A f32 LDS tile re-laid as [2 sub][128 row][16 f32] (64B rows) with the
//      round-13-PROVEN swizzle: chunk (row,c) at slot c ^ ((row>>1)&3), read
//      key (lm>>1)&3, pre-applied to the GLOBAL column (linear LDS dest).
//      Fragment reads are now structurally identical to the measured-zero-
//      conflict B reads (round-14: 0 conflicts).
//  (2) pack2 (RNE, ~6 insts/pair) -> v_cvt_pk_bf16_f32 (1 inst/pair, RNE,
//      m240-verified on gfx950) for the in-loop A f32->bf16 conversion.
// Out-proj keeps the proven bf16-A path.  attn2 unchanged.
// ---------------------------------------------------------------------------

typedef __attribute__((ext_vector_type(8))) short bf16x8;
typedef __attribute__((ext_vector_type(4))) float f32x4;
typedef __attribute__((ext_vector_type(4))) unsigned int u32x4;
typedef __attribute__((address_space(1))) const unsigned int as1_t;
typedef __attribute__((address_space(3))) unsigned int as3_t;

#define DEVI static __device__ __forceinline__

DEVI unsigned short f2bf(float f) {  // RNE f32->bf16 (finite inputs)
  unsigned int u = __float_as_uint(f);
  u += 0x7fffu + ((u >> 16) & 1u);
  return (unsigned short)(u >> 16);
}
DEVI unsigned int pack2(float a, float b) {
  return (unsigned int)f2bf(a) | ((unsigned int)f2bf(b) << 16);
}
// Round-half-up bf16 pair pack (proven rounds 7-15): a -> lo16, b -> hi16.
DEVI unsigned int pk2_rhu(float a, float b) {
  unsigned int ua = __float_as_uint(a) + 0x8000u;
  unsigned int ub = __float_as_uint(b) + 0x8000u;
  return (ua >> 16) | (ub & 0xffff0000u);
}
// HW packed f32->bf16 (RNE, default MODE): a -> lo16, b -> hi16.
DEVI unsigned int cvtpk(float a, float b) {
  unsigned int r;
  asm("v_cvt_pk_bf16_f32 %0, %1, %2" : "=v"(r) : "v"(a), "v"(b));
  return r;
}

DEVI bf16x8 u2bf(u32x4 v) {
  union { u32x4 u; bf16x8 b; } c;
  c.u = v;
  return c.b;
}

DEVI void gload_lds16(const void* g, void* l) {
  __builtin_amdgcn_global_load_lds((as1_t*)g, (as3_t*)l, 16, 0, 0);
}

DEVI float fast_tanh(float x) {  // round-5-proven form
  float ax = fabsf(x);
  float e = __expf(2.0f * ax);
  float r = __builtin_fmaf(-2.0f, __builtin_amdgcn_rcpf(e + 1.0f), 1.0f);
  return copysignf(r, x);
}

// ------------------------- weight f32 -> bf16 ------------------------------
__global__ void cvt_w4(const float* __restrict__ w0, const float* __restrict__ w1,
                       const float* __restrict__ w2, const float* __restrict__ w3,
                       unsigned short* __restrict__ o0, unsigned short* __restrict__ o1,
                       unsigned short* __restrict__ o2, unsigned short* __restrict__ o3) {
  int i = blockIdx.x * 256 + threadIdx.x;
  if (i >= 262144) return;
  f32x4 v;
  uint2 a;
  v = ((const f32x4*)w0)[i]; a.x = pack2(v[0], v[1]); a.y = pack2(v[2], v[3]);
  *(uint2*)(o0 + 4 * (size_t)i) = a;
  v = ((const f32x4*)w1)[i]; a.x = pack2(v[0], v[1]); a.y = pack2(v[2], v[3]);
  *(uint2*)(o1 + 4 * (size_t)i) = a;
  v = ((const f32x4*)w2)[i]; a.x = pack2(v[0], v[1]); a.y = pack2(v[2], v[3]);
  *(uint2*)(o2 + 4 * (size_t)i) = a;
  v = ((const f32x4*)w3)[i]; a.x = pack2(v[0], v[1]); a.y = pack2(v[2], v[3]);
  *(uint2*)(o3 + 4 * (size_t)i) = a;
}

// ---------------- C[m,n] = sum_k A[m,k]*W[n,k] + bias[n] -------------------
// OUT_MODE: 0 = f32 row-major, 1 = bf16 row-major, 2 = bf16 per-head V^T.
// ADT: 0 = A is f32 (direct gload_lds staging, cvt_pk at frag load);
//      1 = A is bf16 (round-12-proven path).  SC=1: epilogue x0.125.
// Both paths: counted-vmcnt 2-buffer pipeline, bank-swizzled LDS tiles.
template <int OUT_MODE, int ADT, int SC>
__global__ __launch_bounds__(256, 4) void gemm_bt(
    const void* __restrict__ Ain, const unsigned short* __restrict__ W,
    const float* __restrict__ bias, void* __restrict__ Cout, int N, int K, int nnt) {
  // ADT=1: A bf16 2x8KB + B 2x8KB = 32KB.  ADT=0: A f32 2x16KB + B 2x8KB = 48KB.
  __shared__ __align__(16) char smem[ADT ? 32768 : 49152];
  char* Asb = smem;
  char* Bsb = smem + (ADT ? 16384 : 32768);
  const int tid = (int)threadIdx.x;
  const int lane = tid & 63, wave = tid >> 6;
  const int lm = lane & 15, l4 = lane >> 4;
  const int nb = (int)gridDim.x;
  const int bx = (int)blockIdx.x;
  const int lg = (bx & 7) * (nb >> 3) + (bx >> 3);
  const int mt = lg / nnt, nt = lg % nnt;
  const int wr = wave >> 1, wc = wave & 1;

  f32x4 zero4 = {0.f, 0.f, 0.f, 0.f};
  f32x4 acc[4][4];
#pragma unroll
  for (int i = 0; i < 4; ++i)
#pragma unroll
    for (int j = 0; j < 4; ++j) acc[i][j] = zero4;

  // ---- B staging mapping (both paths): row = tid>>2, 16B chunk = tid&3.
  // T2 swizzle: chunk (row,blk) lives at slot (row, blk ^ ((row>>1)&3)).
  // Linear LDS dest (tid*16) => pre-swizzle the GLOBAL column: scb.
  const int srow = tid >> 2, sblk = tid & 3;
  const int scb = sblk ^ ((srow >> 1) & 3);
  const unsigned short* wpg = W + (size_t)(nt * 128 + srow) * K + scb * 8;
  // fragment-read XOR key (proven): kx = (lm>>1)&3.
  const int kx = (lm >> 1) & 3;

  if (ADT == 0) {
    // ---- A f32 staging: layout [sub][row][slot] = sub*8192 + row*64 + c*16,
    // sub = K-half (cols sub*16 + 0..15), 64B rows -> proven swizzle geometry.
    // 4 gload_lds/thread/K-step; chunk u: sub = u>>1, row = (u&1)*64 + tid>>2,
    // slot = tid&3; global chunk g = slot ^ ((row>>1)&3) = (tid&3)^((tid>>3)&3)
    // (u-independent).  LDS dest linear: u*4096 + tid*16.
    const float* apf = (const float*)Ain +
                       (size_t)(mt * 128 + (tid >> 2)) * K +
                       ((tid & 3) ^ ((tid >> 3) & 3)) * 4;
    const size_t uo1 = (size_t)64 * K;       // u&1 row offset
    const int NT = K >> 5;
#pragma unroll
    for (int t0 = 0; t0 < 2; ++t0) {
      const int kt = t0 * 32;
      gload_lds16(apf + kt, Asb + t0 * 16384 + tid * 16);
      gload_lds16(apf + uo1 + kt, Asb + t0 * 16384 + 4096 + tid * 16);
      gload_lds16(apf + 16 + kt, Asb + t0 * 16384 + 8192 + tid * 16);
      gload_lds16(apf + uo1 + 16 + kt, Asb + t0 * 16384 + 12288 + tid * 16);
      gload_lds16(wpg + kt, Bsb + t0 * 8192 + tid * 16);
      gload_lds16(wpg + (size_t)64 * K + kt, Bsb + t0 * 8192 + 4096 + tid * 16);
    }
    int cur = 0;
    const int asub = (l4 >> 1) * 8192;       // K-half this lane reads
    const int c0 = (l4 & 1) * 2;             // first of 2 global chunks
    const int rd0 = ((c0 ^ kx) * 16);        // swizzled slots
    const int rd1 = (((c0 + 1) ^ kx) * 16);
    for (int t = 0; t < NT; ++t) {
      if (t + 1 < NT)
        asm volatile("s_waitcnt vmcnt(6)" ::: "memory");
      else
        asm volatile("s_waitcnt vmcnt(0)" ::: "memory");
      asm volatile("s_barrier" ::: "memory");
      bf16x8 af[4], bfr[4];
#pragma unroll
      for (int i = 0; i < 4; ++i) {
        const char* ab = Asb + cur * 16384 + asub + (wr * 64 + i * 16 + lm) * 64;
        f32x4 lo = *(const f32x4*)(ab + rd0);
        f32x4 hi = *(const f32x4*)(ab + rd1);
        u32x4 pv = {cvtpk(lo[0], lo[1]), cvtpk(lo[2], lo[3]),
                    cvtpk(hi[0], hi[1]), cvtpk(hi[2], hi[3])};
        af[i] = u2bf(pv);
      }
#pragma unroll
      for (int j = 0; j < 4; ++j)
        bfr[j] = *(const bf16x8*)(Bsb + cur * 8192 + (wc * 64 + j * 16 + lm) * 64 +
                                  ((l4 ^ kx) * 16));
#pragma unroll
      for (int i = 0; i < 4; ++i)
#pragma unroll
        for (int j = 0; j < 4; ++j)
          acc[i][j] = __builtin_amdgcn_mfma_f32_16x16x32_bf16(af[i], bfr[j], acc[i][j], 0, 0, 0);
      asm volatile("s_barrier" ::: "memory");
      if (t + 2 < NT) {
        const int kt = (t + 2) * 32;
        gload_lds16(apf + kt, Asb + cur * 16384 + tid * 16);
        gload_lds16(apf + uo1 + kt, Asb + cur * 16384 + 4096 + tid * 16);
        gload_lds16(apf + 16 + kt, Asb + cur * 16384 + 8192 + tid * 16);
        gload_lds16(apf + uo1 + 16 + kt, Asb + cur * 16384 + 12288 + tid * 16);
        gload_lds16(wpg + kt, Bsb + cur * 8192 + tid * 16);
        gload_lds16(wpg + (size_t)64 * K + kt, Bsb + cur * 8192 + 4096 + tid * 16);
      }
      cur ^= 1;
    }
  } else {
    // ---- bf16-A path (round-12-proven): counted-vmcnt, swizzled tiles ----
    const unsigned short* apg =
        (const unsigned short*)Ain + (size_t)(mt * 128 + srow) * K + scb * 8;
    const int NT = K >> 5;
#pragma unroll
    for (int t0 = 0; t0 < 2; ++t0) {
      const int kt = t0 * 32;
      gload_lds16(apg + kt, Asb + t0 * 8192 + tid * 16);
      gload_lds16(apg + (size_t)64 * K + kt, Asb + t0 * 8192 + 4096 + tid * 16);
      gload_lds16(wpg + kt, Bsb + t0 * 8192 + tid * 16);
      gload_lds16(wpg + (size_t)64 * K + kt, Bsb + t0 * 8192 + 4096 + tid * 16);
    }
    int cur = 0;
    for (int t = 0; t < NT; ++t) {
      if (t + 1 < NT)
        asm volatile("s_waitcnt vmcnt(4)" ::: "memory");
      else
        asm volatile("s_waitcnt vmcnt(0)" ::: "memory");
      asm volatile("s_barrier" ::: "memory");
      bf16x8 af[4], bfr[4];
#pragma unroll
      for (int i = 0; i < 4; ++i)
        af[i] = *(const bf16x8*)(Asb + cur * 8192 + (wr * 64 + i * 16 + lm) * 64 +
                                 ((l4 ^ kx) * 16));
#pragma unroll
      for (int j = 0; j < 4; ++j)
        bfr[j] = *(const bf16x8*)(Bsb + cur * 8192 + (wc * 64 + j * 16 + lm) * 64 +
                                  ((l4 ^ kx) * 16));
#pragma unroll
      for (int i = 0; i < 4; ++i)
#pragma unroll
        for (int j = 0; j < 4; ++j)
          acc[i][j] = __builtin_amdgcn_mfma_f32_16x16x32_bf16(af[i], bfr[j], acc[i][j], 0, 0, 0);
      asm volatile("s_barrier" ::: "memory");
      if (t + 2 < NT) {
        const int kt = (t + 2) * 32;
        gload_lds16(apg + kt, Asb + cur * 8192 + tid * 16);
        gload_lds16(apg + (size_t)64 * K + kt, Asb + cur * 8192 + 4096 + tid * 16);
        gload_lds16(wpg + kt, Bsb + cur * 8192 + tid * 16);
        gload_lds16(wpg + (size_t)64 * K + kt, Bsb + cur * 8192 + 4096 + tid * 16);
      }
      cur ^= 1;
    }
  }

  const int r0 = mt * 128 + wr * 64 + l4 * 4;
  const int c0o = nt * 128 + wc * 64 + lm;
  float bb[4];
#pragma unroll
  for (int j = 0; j < 4; ++j) bb[j] = bias[c0o + j * 16];

  if (OUT_MODE < 2) {
#pragma unroll
    for (int i = 0; i < 4; ++i)
#pragma unroll
      for (int j = 0; j < 4; ++j)
#pragma unroll
        for (int p = 0; p < 4; ++p) {
          size_t idx = (size_t)(r0 + i * 16 + p) * N + (size_t)(c0o + j * 16);
          float v = acc[i][j][p] + bb[j];
          if (SC) v *= 0.125f;  // exact exponent shift; bf16(v/8) == bf16(v)/8
          if (OUT_MODE == 1)
            ((unsigned short*)Cout)[idx] = f2bf(v);
          else
            ((float*)Cout)[idx] = v;
        }
  } else {
    // V^T per-head tiles: vt[((b*20+r)*16+h)*4096 + d*64 + t], t = i*16+l4*4+p
    const int grow = mt * 128 + wr * 64;
    const int bidx = grow / 1280;
    const int rv = (grow % 1280) / 64;
    const int hh = (nt * 128 + wc * 64) / 64;
    unsigned short* vt = (unsigned short*)Cout;
    const size_t base = ((size_t)(bidx * 20 + rv) * 16 + hh) * 4096;
#pragma unroll
    for (int j = 0; j < 4; ++j) {
      const int d = lm + j * 16;
#pragma unroll
      for (int i = 0; i < 4; ++i) {
        uint2 wv;
        wv.x = pack2(acc[i][j][0] + bb[j], acc[i][j][1] + bb[j]);
        wv.y = pack2(acc[i][j][2] + bb[j], acc[i][j][3] + bb[j]);
        *(uint2*)(vt + base + (size_t)d * 64 + i * 16 + l4 * 4) = wv;
      }
    }
  }
}

// ----------------------------- fused attention -----------------------------
// One block per (h, b); 8 waves, wave w owns q rows [16w,16w+16).
// Swapped-operand MFMAs so q = lane&15 everywhere; online softmax over r.
// LDS (48KB): kv_s[2][K,V] 32KB; pa_s 16KB; q/sa^T staging overlays.
// Active-review compaction: reviews with mask==1 (when any mask==0 exists in
// row b) have pooled weight exactly 0.0f (expf(-1e30 - max) underflows) ->
// skipped entirely.  Bitmask is uniform per block (depends only on b).
__global__ __launch_bounds__(512, 4) void attn2(
    const unsigned short* __restrict__ qb, const unsigned short* __restrict__ kb,
    const unsigned short* __restrict__ vtg, const int* __restrict__ mask,
    const int* __restrict__ mask2, const float* __restrict__ sa_a,
    const float* __restrict__ sa_b, unsigned short* __restrict__ merged) {
  const int h = (int)blockIdx.x;
  const int b = (int)blockIdx.y;
  const int tid = (int)threadIdx.x;
  const int lane = tid & 63, wave = tid >> 6;
  const int lm = lane & 15, l4 = lane >> 4;
  const int sw = (lm & 7) << 4;

  __shared__ unsigned short kv_s[2][2][64 * 64];  // [buf][0=K [t][d], 1=V^T [d][t]]
  __shared__ unsigned short pa_s[8 * 16 * 64];    // wave-private P/att rows

  char* kvb0 = (char*)kv_s;          // buf stride 16384; V^T at +8192
  char* qreg = (char*)kv_s + 16384;  // q staging region = buf1 (dead after hoist)
  char* satb = (char*)pa_s;          // sa^T staging (dead after hoist)

  // ---- active-review bitmask (uniform across the block) ----
  unsigned am = 0u;
#pragma unroll
  for (int rr = 0; rr < 20; ++rr)
    am |= (mask[b * 20 + rr] == 0) ? (1u << rr) : 0u;
  // az (= some review has mask==0) => only those reviews survive; else all.
  const unsigned act = am ? am : 0xFFFFFu;

  // ---- stage Q into qreg (pre-swizzled source columns) ----
#pragma unroll
  for (int s = 0; s < 2; ++s) {
    int idx = s * 512 + tid, row = idx >> 3, blk = idx & 7;
    int cb = blk ^ (row & 7);
    gload_lds16(qb + (size_t)(b * 128 + row) * 1024 + h * 64 + cb * 8, qreg + idx * 16);
  }
  // ---- stage sa^T into satb: sat[jj][d] = sa_a[d][jj], swizzled ----
#pragma unroll
  for (int s = 0; s < 8; ++s) {
    int idx = s * 512 + tid, jj = idx & 63, d = idx >> 6;
    *(unsigned short*)(satb + jj * 128 + ((d * 2) ^ ((jj & 7) << 4))) =
        f2bf(sa_a[d * 64 + jj]);
  }
  // ---- stage first ACTIVE review K/V into buf0 ----
  const int srow = tid >> 3, sblk = tid & 7;
  const int scb = sblk ^ (srow & 7);
  int r = (int)__builtin_ctz(act);
  unsigned rem = act & (act - 1u);
  gload_lds16(kb + ((size_t)(b * 20 + r) * 64 + srow) * 1024 + h * 64 + scb * 8,
              kvb0 + tid * 16);
  gload_lds16(vtg + ((size_t)(b * 20 + r) * 16 + h) * 4096 + srow * 64 + scb * 8,
              kvb0 + 8192 + tid * 16);

  f32x4 sbv[4];
#pragma unroll
  for (int i = 0; i < 4; ++i) sbv[i] = *(const f32x4*)(sa_b + i * 16 + l4 * 4);

  __syncthreads();  // qreg, satb, buf0 all visible

  // ---- hoist Q B-fragments and sa^T A-fragments to registers ----
  const char* qrp = qreg + (wave * 16 + lm) * 128;
  bf16x8 qf[2];
  qf[0] = *(const bf16x8*)(qrp + ((l4 * 16) ^ sw));
  qf[1] = *(const bf16x8*)(qrp + ((64 + l4 * 16) ^ sw));
  bf16x8 sfr[2][4];
#pragma unroll
  for (int kk = 0; kk < 2; ++kk)
#pragma unroll
    for (int i = 0; i < 4; ++i)
      sfr[kk][i] = *(const bf16x8*)(satb + (i * 16 + lm) * 128 +
                                    ((kk * 64 + l4 * 16) ^ sw));
  asm volatile("s_waitcnt lgkmcnt(0)" ::: "memory");  // hoist reads retired
  __syncthreads();  // all waves done -> qreg/satb reusable as buf1 / P-rows

  char* pw = (char*)pa_s + wave * 2048 + lm * 128;  // wave-private row q=lm

  f32x4 zero4 = {0.f, 0.f, 0.f, 0.f};
  f32x4 Pacc[4];
#pragma unroll
  for (int i = 0; i < 4; ++i) Pacc[i] = zero4;
  float m_run = -3.0e38f, s_run = 0.0f;

  int it = 0;
  for (;;) {
    const int pb = it & 1;
    if (it) __syncthreads();  // buf[pb] staged; all waves done with buf[1-pb]
    const int nr = rem ? (int)__builtin_ctz(rem) : -1;
    if (nr >= 0) {  // stage next active review (flies under this one's compute)
      const int nbuf = pb ^ 1;
      gload_lds16(kb + ((size_t)(b * 20 + nr) * 64 + srow) * 1024 + h * 64 + scb * 8,
                  kvb0 + nbuf * 16384 + tid * 16);
      gload_lds16(vtg + ((size_t)(b * 20 + nr) * 16 + h) * 4096 + srow * 64 + scb * 8,
                  kvb0 + nbuf * 16384 + 8192 + tid * 16);
    }
    const char* kbse = kvb0 + pb * 16384;
    const char* vbse = kvb0 + pb * 16384 + 8192;

    // ---- S^T = mfma(K, Q): rows t, col q (q pre-scaled by 1/8) ----
    f32x4 sc[4];
#pragma unroll
    for (int i = 0; i < 4; ++i) sc[i] = zero4;
    __builtin_amdgcn_s_setprio(1);
#pragma unroll
    for (int kk = 0; kk < 2; ++kk) {
      bf16x8 kf[4];
#pragma unroll
      for (int i = 0; i < 4; ++i)
        kf[i] = *(const bf16x8*)(kbse + (i * 16 + lm) * 128 + ((kk * 64 + l4 * 16) ^ sw));
#pragma unroll
      for (int i = 0; i < 4; ++i)
        sc[i] = __builtin_amdgcn_mfma_f32_16x16x32_bf16(kf[i], qf[kk], sc[i], 0, 0, 0);
    }
    __builtin_amdgcn_s_setprio(0);

    // ---- token mask (scores already scaled) + softmax over t ----
    const int mbase = (b * 20 + r) * 64;
#pragma unroll
    for (int i = 0; i < 4; ++i) {
      int4 m2 = *(const int4*)(mask2 + mbase + i * 16 + l4 * 4);
      sc[i][0] = (m2.x == 0) ? -1e20f : sc[i][0];
      sc[i][1] = (m2.y == 0) ? -1e20f : sc[i][1];
      sc[i][2] = (m2.z == 0) ? -1e20f : sc[i][2];
      sc[i][3] = (m2.w == 0) ? -1e20f : sc[i][3];
    }
    float mx = sc[0][0];
#pragma unroll
    for (int i = 0; i < 4; ++i)
#pragma unroll
      for (int p = 0; p < 4; ++p) mx = fmaxf(mx, sc[i][p]);
    mx = fmaxf(mx, __shfl_xor(mx, 16));
    mx = fmaxf(mx, __shfl_xor(mx, 32));
    float sum = 0.f;
#pragma unroll
    for (int i = 0; i < 4; ++i)
#pragma unroll
      for (int p = 0; p < 4; ++p) {
        float e = __expf(sc[i][p] - mx);
        sc[i][p] = e;
        sum += e;
      }
    sum += __shfl_xor(sum, 16);
    sum += __shfl_xor(sum, 32);
    const float pinv = __builtin_amdgcn_rcpf(sum);

    // ---- P -> wave-private LDS [q][t], packed 8B swizzled writes ----
#pragma unroll
    for (int i = 0; i < 4; ++i) {
      uint2 wv;
      wv.x = pk2_rhu(sc[i][0] * pinv, sc[i][1] * pinv);
      wv.y = pk2_rhu(sc[i][2] * pinv, sc[i][3] * pinv);
      *(uint2*)(pw + ((i * 32 + l4 * 8) ^ sw)) = wv;
    }

    // ---- att^T = mfma(V^T, P): rows d, col q ----
    f32x4 av[4];
#pragma unroll
    for (int i = 0; i < 4; ++i) av[i] = zero4;
    __builtin_amdgcn_s_setprio(1);
#pragma unroll
    for (int kk = 0; kk < 2; ++kk) {
      bf16x8 pf = *(const bf16x8*)(pw + ((kk * 64 + l4 * 16) ^ sw));
      bf16x8 vf[4];
#pragma unroll
      for (int i = 0; i < 4; ++i)
        vf[i] = *(const bf16x8*)(vbse + (i * 16 + lm) * 128 + ((kk * 64 + l4 * 16) ^ sw));
#pragma unroll
      for (int i = 0; i < 4; ++i)
        av[i] = __builtin_amdgcn_mfma_f32_16x16x32_bf16(vf[i], pf, av[i], 0, 0, 0);
    }
    __builtin_amdgcn_s_setprio(0);

    // ---- att -> same wave-private LDS [q][d] (P already consumed) ----
#pragma unroll
    for (int i = 0; i < 4; ++i) {
      uint2 wv;
      wv.x = pk2_rhu(av[i][0], av[i][1]);
      wv.y = pk2_rhu(av[i][2], av[i][3]);
      *(uint2*)(pw + ((i * 32 + l4 * 8) ^ sw)) = wv;
    }

    // ---- e^T = mfma(sa^T, att): rows jj, col q ----
    f32x4 ep[4];
#pragma unroll
    for (int i = 0; i < 4; ++i) ep[i] = zero4;
    __builtin_amdgcn_s_setprio(1);
#pragma unroll
    for (int kk = 0; kk < 2; ++kk) {
      bf16x8 afr = *(const bf16x8*)(pw + ((kk * 64 + l4 * 16) ^ sw));
#pragma unroll
      for (int i = 0; i < 4; ++i)
        ep[i] = __builtin_amdgcn_mfma_f32_16x16x32_bf16(sfr[kk][i], afr, ep[i], 0, 0, 0);
    }
    __builtin_amdgcn_s_setprio(0);
    float a = 0.f;
#pragma unroll
    for (int i = 0; i < 4; ++i)
#pragma unroll
      for (int p = 0; p < 4; ++p) a += fast_tanh(ep[i][p]) * sbv[i][p];
    a += __shfl_xor(a, 16);
    a += __shfl_xor(a, 32);

    // ---- exact online softmax update over active reviews ----
    // All surviving reviews have add_mask == 0, so e_r = a directly.
    const float e_r = a;
    const float mnew = fmaxf(m_run, e_r);
    const float scl = __expf(m_run - mnew);
    const float w = __expf(e_r - mnew);
    s_run = s_run * scl + w;
#pragma unroll
    for (int i = 0; i < 4; ++i)
#pragma unroll
      for (int p = 0; p < 4; ++p) Pacc[i][p] = Pacc[i][p] * scl + w * av[i][p];
    m_run = mnew;

    if (nr < 0) break;
    r = nr;
    rem &= rem - 1u;
    ++it;
  }

  // ---- merged[b*128+q][h*64+d] = bf16(Pacc / s) ----
  const float inv_s = __builtin_amdgcn_rcpf(s_run);
  unsigned short* mrow = merged + (size_t)(b * 128 + wave * 16 + lm) * 1024 + h * 64;
#pragma unroll
  for (int i = 0; i < 4; ++i) {
    uint2 o;
    o.x = pk2_rhu(Pacc[i][0] * inv_s, Pacc[i][1] * inv_s);
    o.y = pk2_rhu(Pacc[i][2] * inv_s, Pacc[i][3] * inv_s);
    *(uint2*)(mrow + i * 16 + l4 * 4) = o;
  }
}

// ---------------------------------------------------------------------------
extern "C" void kernel_launch(void* const* d_in, const int* in_sizes, int n_in,
                              void* d_out, int out_size, void* d_ws, size_t ws_size,
                              hipStream_t stream) {
  (void)in_sizes; (void)n_in; (void)out_size; (void)ws_size;
  const float* query = (const float*)d_in[0];
  const float* key   = (const float*)d_in[1];
  const float* value = (const float*)d_in[2];
  const int*   mask  = (const int*)d_in[3];
  const int*   mask2 = (const int*)d_in[4];
  const float* Wq = (const float*)d_in[5];
  const float* bq = (const float*)d_in[6];
  const float* Wk = (const float*)d_in[7];
  const float* bk = (const float*)d_in[8];
  const float* Wv = (const float*)d_in[9];
  const float* bv = (const float*)d_in[10];
  const float* Wo = (const float*)d_in[11];
  const float* bo = (const float*)d_in[12];
  const float* sa_a = (const float*)d_in[13];
  const float* sa_b = (const float*)d_in[14];

  char* ws = (char*)d_ws;
  size_t off = 0;
  auto carve = [&](size_t bytes) -> char* {
    char* p = ws + off;
    off += (bytes + 255) & ~(size_t)255;
    return p;
  };
  unsigned short* wq_b = (unsigned short*)carve((size_t)1024 * 1024 * 2);
  unsigned short* wk_b = (unsigned short*)carve((size_t)1024 * 1024 * 2);
  unsigned short* wv_b = (unsigned short*)carve((size_t)1024 * 1024 * 2);
  unsigned short* wo_b = (unsigned short*)carve((size_t)1024 * 1024 * 2);
  unsigned short* q_b  = (unsigned short*)carve((size_t)4096 * 1024 * 2);
  unsigned short* k_b  = (unsigned short*)carve((size_t)40960 * 1024 * 2);
  unsigned short* vt_g = (unsigned short*)carve((size_t)40960 * 1024 * 2);
  unsigned short* mrg  = (unsigned short*)carve((size_t)4096 * 1024 * 2);

  cvt_w4<<<1024, 256, 0, stream>>>(Wq, Wk, Wv, Wo, wq_b, wk_b, wv_b, wo_b);

  // f32-A direct GEMMs (no cvt_bf16 passes)
  gemm_bt<1, 0, 1><<<dim3(32 * 8), 256, 0, stream>>>(query, wq_b, bq, q_b, 1024, 1024, 8);
  gemm_bt<1, 0, 0><<<dim3(320 * 8), 256, 0, stream>>>(key, wk_b, bk, k_b, 1024, 1024, 8);
  gemm_bt<2, 0, 0><<<dim3(320 * 8), 256, 0, stream>>>(value, wv_b, bv, vt_g, 1024, 1024, 8);

  attn2<<<dim3(16, 32), 512, 0, stream>>>(q_b, k_b, vt_g, mask, mask2, sa_a, sa_b, mrg);

  // out projection: A (mrg) is bf16 -> proven bf16-A path
  gemm_bt<0, 1, 0><<<dim3(32 * 8), 256, 0, stream>>>(mrg, wo_b, bo, d_out, 1024, 1024, 8);
}